// Round 14
// baseline (244.016 us; speedup 1.0000x reference)
//
#include <hip/hip_runtime.h>

#define NSMP 44100
#define NKNOT 100
#define NIV  (NKNOT - 1)      // 99 spline intervals
#define NCC 6
#define NAA 7
#define RING 1024             // logical ring; mirrored into 2048 floats
#define NTH 320
#define SEG ((NSMP + NTH - 1) / NTH)   // 138
#define WS_NEEDED ((size_t)NSMP * 32)  // recA + recB (float4 each)

__device__ __forceinline__ float sigm(float x) { return 1.0f / (1.0f + expf(-x)); }

__device__ __forceinline__ void lean_barrier() {
    // drain LDS ops only (ring visibility); global loads/stores stay in flight
    asm volatile("s_waitcnt lgkmcnt(0)" ::: "memory");
    __builtin_amdgcn_s_barrier();
    __builtin_amdgcn_sched_barrier(0);
}

// =====================  shared prep (A, B, B')  ============================
__device__ __forceinline__ void prep_spline(
    const float* __restrict__ dlf, const float* __restrict__ rg,
    const float* __restrict__ rcf,
    float (*P)[NAA], float (*M)[NAA], float* CPs, float* IMs,
    float4 (*CO)[8], int* s_minz, int tid)
{
    const float H = 1.0f / 99.0f;
    if (tid < NKNOT) {
        float g = sigm(rg[0]);
        float s[NCC];
        float sum = 0.0f;
#pragma unroll
        for (int j = 0; j < NCC; ++j) { s[j] = sigm(rcf[tid * NCC + j]); sum += s[j]; }
        P[tid][0] = dlf[tid];
#pragma unroll
        for (int j = 0; j < NCC; ++j) P[tid][j + 1] = s[j] / sum * g;
    }
    // Thomas c' coefficients converge by ~10 iterations -> parallel
    if (tid < NKNOT - 2) {
        float cp = 0.25f;
        int n = tid; if (n > 10) n = 10;
        for (int k = 0; k < n; ++k) cp = 1.0f / (4.0f - cp);
        CPs[tid] = cp;
    }
    __syncthreads();
    if (tid >= 1 && tid < NKNOT - 2) IMs[tid] = 99.0f / (4.0f - CPs[tid - 1]);
    __syncthreads();
    if (tid < NAA) {
        int c = tid;
        float rhs0  = 6.0f * (P[2][c] - 2.0f * P[1][c] + P[0][c]) * 99.0f;
        float dprev = rhs0 * 24.75f;
        M[1][c] = dprev;
        for (int i = 1; i < NKNOT - 2; ++i) {
            float rhs = 6.0f * (P[i + 2][c] - 2.0f * P[i + 1][c] + P[i][c]) * 99.0f;
            float d   = (rhs - H * dprev) * IMs[i];
            M[i + 1][c] = d;
            dprev = d;
        }
        float nxt = M[NKNOT - 2][c];
        for (int i = NKNOT - 4; i >= 0; --i) {
            float v = M[i + 1][c] - CPs[i] * nxt;
            M[i + 1][c] = v;
            nxt = v;
        }
        M[0][c] = 0.0f;
        M[NKNOT - 1][c] = 0.0f;
    }
    __syncthreads();
    // min-delay lower bound: s(x) >= min(y0,y1) - (h^2/8) max|s''|
    if (tid < NIV) {
        float lb = fminf(P[tid][0], P[tid + 1][0])
                 - (H * H * 0.125f) * fmaxf(fabsf(M[tid][0]), fabsf(M[tid + 1][0]));
        atomicMin(s_minz, (int)floorf(lb));
    }
    for (int iv = tid; iv < NIV; iv += blockDim.x) {
#pragma unroll
        for (int c = 0; c < NAA; ++c) {
            float y0 = P[iv][c], y1 = P[iv + 1][c];
            float m0 = M[iv][c], m1 = M[iv + 1][c];
            float b  = (y1 - y0) * 99.0f - H * (2.0f * m0 + m1) * (1.0f / 6.0f);
            CO[iv][c] = make_float4(y0, b, 0.5f * m0, (m1 - m0) * (99.0f / 6.0f));
        }
    }
    __syncthreads();
}

// ============================  fast kernel  ================================

__global__ __launch_bounds__(NTH, 1) void diffks_fast(
    const float* __restrict__ dlf, const float* __restrict__ rg,
    const float* __restrict__ rcf, const float* __restrict__ exc,
    const float* __restrict__ ecoef, float* __restrict__ out,
    float4* __restrict__ recA, float4* __restrict__ recB)
{
    __shared__ float  P[NKNOT][NAA];
    __shared__ float  M[NKNOT][NAA];
    __shared__ float4 CO[NIV][8];
    __shared__ float  ring[2 * RING];
    __shared__ float  CPs[NKNOT - 2];
    __shared__ float  IMs[NKNOT - 2];
    __shared__ float  wpS[NTH / 64], wqS[NTH / 64];
    __shared__ int    s_minz;

    const int tid  = threadIdx.x;
    const int lane = tid & 63;
    const int wav  = tid >> 6;
    const float H   = 1.0f / 99.0f;
    const float INV = 1.0f / (float)(NSMP - 1);

    if (tid == 0) s_minz = 0x7fffffff;
    for (int i = tid; i < 2 * RING; i += NTH) ring[i] = 0.0f;

    prep_spline(dlf, rg, rcf, P, M, CPs, IMs, CO, &s_minz, tid);

    // ---- Phase C: tap records for ALL samples -> recA/recB (d_ws) --------
    // (R8-proven: per-thread, cidx-cached CO registers.)
    {
        int start = tid * SEG;
        int end   = min(start + SEG, NSMP);
        int cidx = -1;
        float4 k0, k1, k2, k3, k4, k5, k6;
        k0 = k1 = k2 = k3 = k4 = k5 = k6 = make_float4(0.f, 0.f, 0.f, 0.f);
        for (int t = start; t < end; ++t) {
            float tt = (float)t * INV;
            int idx = (int)(tt * 99.0f); if (idx > NIV - 1) idx = NIV - 1;
            if (idx != cidx) {
                k0 = CO[idx][0]; k1 = CO[idx][1]; k2 = CO[idx][2]; k3 = CO[idx][3];
                k4 = CO[idx][4]; k5 = CO[idx][5]; k6 = CO[idx][6];
                cidx = idx;
            }
            float f = tt - (float)idx * H;
            float r0 = k0.x + f * (k0.y + f * (k0.z + f * k0.w));
            float r1 = k1.x + f * (k1.y + f * (k1.z + f * k1.w));
            float r2 = k2.x + f * (k2.y + f * (k2.z + f * k2.w));
            float r3 = k3.x + f * (k3.y + f * (k3.z + f * k3.w));
            float r4 = k4.x + f * (k4.y + f * (k4.z + f * k4.w));
            float r5 = k5.x + f * (k5.y + f * (k5.z + f * k5.w));
            float r6 = k6.x + f * (k6.y + f * (k6.z + f * k6.w));
            float fl = floorf(r0);
            float alfa = r0 - fl, om = 1.0f - alfa;
            // reversed taps: w_d multiplies ring[ra + d]
            float w6 = -om * r1;
            float w5 = -(alfa * r1 + om * r2);
            float w4 = -(alfa * r2 + om * r3);
            float w3 = -(alfa * r3 + om * r4);
            float w2 = -(alfa * r4 + om * r5);
            float w1 = -(alfa * r5 + om * r6);
            float w0 = -alfa * r6;
            int ra = (t - 1 - (int)fl - 6) & (RING - 1);
            recA[t] = make_float4(w0, w1, w2, w3);
            recB[t] = make_float4(w4, w5, w6, __int_as_float(ra));
        }
    }

    // ---- Phase D: order-1 LPC (segmented affine scan); x2 -> out ---------
    {
        int start = tid * SEG;
        int end   = min(start + SEG, NSMP);
        float p = 1.0f, q = 0.0f;
#pragma unroll 4
        for (int t = start; t < end; ++t) {
            float a2 = ecoef[t];
            q = fmaf(-a2, q, exc[t]);
            p *= -a2;
        }
#pragma unroll
        for (int d = 1; d < 64; d <<= 1) {
            float pp = __shfl_up(p, d);
            float qq = __shfl_up(q, d);
            if (lane >= d) { q = fmaf(p, qq, q); p *= pp; }
        }
        if (lane == 63) { wpS[wav] = p; wqS[wav] = q; }
        float pe = __shfl_up(p, 1);
        float qe = __shfl_up(q, 1);
        if (lane == 0) { pe = 1.0f; qe = 0.0f; }
        __syncthreads();
        float v = 0.0f;
        for (int w = 0; w < wav; ++w) v = fmaf(wpS[w], v, wqS[w]);
        float y = fmaf(pe, v, qe);
#pragma unroll 4
        for (int t = start; t < end; ++t) {
            y = fmaf(-ecoef[t], y, exc[t]);
            out[t] = y;                        // stage x2 in d_out
        }
    }
    __syncthreads();   // recs + x2 + s_minz all visible (full drain, once)

    // ---- Phase E: SINGLE WAVE, zero barriers; plain C++ memory ops --------
    // Same-wave DS ordering + explicit lgkm drain per window replaces the
    // block barrier. ONLY delta vs R9 (failed): plain out[t]= stores instead
    // of inline-asm gstore.
    if (tid >= 64) return;                     // waves 1..4 done

    int C = s_minz + 1;
    if (C > 320) C = 320;
    if (C < 1)  C = 1;
    const int NW = (NSMP + C - 1) / C;

    float4 a[5], b[5];
    float  x[5];
    // preload window 0 (all indices < NSMP)
#pragma unroll
    for (int r = 0; r < 5; ++r) {
        int pos = r * 64 + lane;
        int tc = (pos < C) ? pos : 0;
        a[r] = recA[tc]; b[r] = recB[tc]; x[r] = out[tc];
    }

#pragma unroll 1
    for (int w = 0; w < NW; ++w) {
        // prefetch window w+1 (global loads; consumed at loop end)
        float4 na[5], nb[5];
        float  nx[5];
#pragma unroll
        for (int r = 0; r < 5; ++r) {
            int pos = r * 64 + lane;
            int t = (w + 1) * C + pos;
            int tc = (pos < C && t < NSMP) ? t : 0;
            na[r] = recA[tc]; nb[r] = recB[tc]; nx[r] = out[tc];
        }
        // current window: ring reads + FMA tree + ring/mirror/out writes
#pragma unroll
        for (int r = 0; r < 5; ++r) {
            int pos = r * 64 + lane;
            int t = w * C + pos;
            const float* rp = &ring[(unsigned)__float_as_int(b[r].w)];
            float y0 = rp[0], y1 = rp[1], y2 = rp[2], y3 = rp[3];
            float y4 = rp[4], y5 = rp[5], y6 = rp[6];
            float s = ((a[r].x * y0 + a[r].y * y1) + (a[r].z * y2 + a[r].w * y3))
                    + ((b[r].x * y4 + b[r].y * y5) + b[r].z * y6);
            float acc = x[r] - s;
            if (pos < C && t < NSMP) {
                int wi = t & (RING - 1);
                ring[wi]        = acc;
                ring[wi + RING] = acc;   // mirror: reads never wrap
                out[t] = acc;            // plain store (delta vs R9's gstore)
            }
        }
        // write->next-read ordering within the wave
        asm volatile("s_waitcnt lgkmcnt(0)" ::: "memory");
        __builtin_amdgcn_sched_barrier(0);
#pragma unroll
        for (int r = 0; r < 5; ++r) { a[r] = na[r]; b[r] = nb[r]; x[r] = nx[r]; }
    }
}

// ================  fallback (round-4 proven path, no d_ws)  ================

#define FNTH 320
#define FSEG ((NSMP + FNTH - 1) / FNTH)
#define FGW 8

__device__ __forceinline__ void compute_rec_f(const float4 (*CO)[8], int t, bool a,
                                              float* wr, int* raOut) {
    const float H   = 1.0f / 99.0f;
    const float INV = 1.0f / (float)(NSMP - 1);
    if (!a) {
#pragma unroll
        for (int d = 0; d < NAA; ++d) wr[d] = 0.0f;
        *raOut = 0;
        return;
    }
    float tt = (float)t * INV;
    int idx = (int)(tt * 99.0f); if (idx > NIV - 1) idx = NIV - 1;
    float f = tt - (float)idx * H;
    float r[NAA];
#pragma unroll
    for (int c = 0; c < NAA; ++c) {
        float4 k = CO[idx][c];
        r[c] = k.x + f * (k.y + f * (k.z + f * k.w));
    }
    float fl = floorf(r[0]);
    float alfa = r[0] - fl, om = 1.0f - alfa;
    wr[6] = -om * r[1];
    wr[5] = -(alfa * r[1] + om * r[2]);
    wr[4] = -(alfa * r[2] + om * r[3]);
    wr[3] = -(alfa * r[3] + om * r[4]);
    wr[2] = -(alfa * r[4] + om * r[5]);
    wr[1] = -(alfa * r[5] + om * r[6]);
    wr[0] = -alfa * r[6];
    *raOut = (t - 1 - (int)fl - 6) & (RING - 1);
}

__global__ __launch_bounds__(FNTH, 1) void diffks_fallback(
    const float* __restrict__ dlf, const float* __restrict__ rg,
    const float* __restrict__ rcf, const float* __restrict__ exc,
    const float* __restrict__ ecoef, float* __restrict__ out)
{
    __shared__ float  P[NKNOT][NAA];
    __shared__ float  M[NKNOT][NAA];
    __shared__ float4 CO[NIV][8];
    __shared__ float  ring[2 * RING];
    __shared__ float  CPs[NKNOT - 2];
    __shared__ float  IMs[NKNOT - 2];
    __shared__ float  wpS[FNTH / 64], wqS[FNTH / 64];
    __shared__ int    s_minz;

    const int tid  = threadIdx.x;
    const int lane = tid & 63;
    const int wav  = tid >> 6;

    if (tid == 0) s_minz = 0x7fffffff;
    for (int i = tid; i < 2 * RING; i += FNTH) ring[i] = 0.0f;

    prep_spline(dlf, rg, rcf, P, M, CPs, IMs, CO, &s_minz, tid);

    {
        int start = tid * FSEG;
        int end   = min(start + FSEG, NSMP);
        float p = 1.0f, q = 0.0f;
#pragma unroll 4
        for (int t = start; t < end; ++t) {
            float a2 = ecoef[t];
            q = fmaf(-a2, q, exc[t]);
            p *= -a2;
        }
#pragma unroll
        for (int d = 1; d < 64; d <<= 1) {
            float pp = __shfl_up(p, d);
            float qq = __shfl_up(q, d);
            if (lane >= d) { q = fmaf(p, qq, q); p *= pp; }
        }
        if (lane == 63) { wpS[wav] = p; wqS[wav] = q; }
        float pe = __shfl_up(p, 1);
        float qe = __shfl_up(q, 1);
        if (lane == 0) { pe = 1.0f; qe = 0.0f; }
        __syncthreads();
        float v = 0.0f;
        for (int w = 0; w < wav; ++w) v = fmaf(wpS[w], v, wqS[w]);
        float y = fmaf(pe, v, qe);
#pragma unroll 4
        for (int t = start; t < end; ++t) {
            y = fmaf(-ecoef[t], y, exc[t]);
            out[t] = y;
        }
    }
    __syncthreads();

    int C = s_minz + 1;
    if (C > FNTH) C = FNTH;
    if (C < 1)  C = 1;
    const int NW   = (NSMP + C - 1) / C;
    const int NCH  = (NW + FGW - 1) / FGW;
    const int step = FGW * C;

    float  wA[FGW][NAA];
    int    raA[FGW];
    float  xsA[FGW];
    int    wiA[FGW];
    bool   aA[FGW];
    float* opA[FGW];
#pragma unroll
    for (int g = 0; g < FGW; ++g) {
        int t = g * C + tid;
        bool a = (tid < C) && (t < NSMP);
        compute_rec_f(CO, t, a, wA[g], &raA[g]);
        xsA[g]  = a ? out[t] : 0.0f;
        wiA[g]  = t & (RING - 1);
        aA[g]   = a;
        opA[g]  = out + t;
    }
    for (int ch = 0; ch < NCH; ++ch) {
        const int Wn = (ch + 1) * step;
        float  nx[FGW]; int ntv[FGW]; int nwi[FGW]; bool nav[FGW]; float* nop[FGW];
#pragma unroll
        for (int g = 0; g < FGW; ++g) {
            int tn = Wn + g * C + tid;
            bool an = (tid < C) && (tn < NSMP);
            nx[g]  = an ? out[tn] : 0.0f;
            ntv[g] = tn; nwi[g] = tn & (RING - 1); nav[g] = an; nop[g] = out + tn;
        }
        float wB[FGW][NAA]; int raB[FGW];
#pragma unroll
        for (int g = 0; g < FGW; ++g) {
            const float* rp = &ring[(unsigned)raA[g]];
            float y0 = rp[0], y1 = rp[1], y2 = rp[2], y3 = rp[3];
            float y4 = rp[4], y5 = rp[5], y6 = rp[6];
            compute_rec_f(CO, ntv[g], nav[g], wB[g], &raB[g]);
            float s = ((wA[g][0] * y0 + wA[g][1] * y1) + (wA[g][2] * y2 + wA[g][3] * y3))
                    + ((wA[g][4] * y4 + wA[g][5] * y5) + wA[g][6] * y6);
            float acc = xsA[g] - s;
            if (aA[g]) {
                ring[wiA[g]] = acc;
                ring[wiA[g] + RING] = acc;
                *opA[g] = acc;
            }
            lean_barrier();
        }
#pragma unroll
        for (int g = 0; g < FGW; ++g) {
#pragma unroll
            for (int d = 0; d < NAA; ++d) wA[g][d] = wB[g][d];
            raA[g] = raB[g]; xsA[g] = nx[g]; wiA[g] = nwi[g];
            aA[g] = nav[g]; opA[g] = nop[g];
        }
    }
}

extern "C" void kernel_launch(void* const* d_in, const int* in_sizes, int n_in,
                              void* d_out, int out_size, void* d_ws, size_t ws_size,
                              hipStream_t stream) {
    const float* dlf   = (const float*)d_in[0];
    const float* rg    = (const float*)d_in[1];
    const float* rcf   = (const float*)d_in[2];
    const float* exc   = (const float*)d_in[3];
    const float* ecoef = (const float*)d_in[4];
    float* out = (float*)d_out;

    if (d_ws != nullptr && ws_size >= WS_NEEDED) {
        float4* recA = (float4*)d_ws;
        float4* recB = (float4*)((char*)d_ws + (size_t)NSMP * 16);
        hipLaunchKernelGGL(diffks_fast, dim3(1), dim3(NTH), 0, stream,
                           dlf, rg, rcf, exc, ecoef, out, recA, recB);
    } else {
        hipLaunchKernelGGL(diffks_fallback, dim3(1), dim3(FNTH), 0, stream,
                           dlf, rg, rcf, exc, ecoef, out);
    }
}

// Round 15
// 238.936 us; speedup vs baseline: 1.0213x; 1.0213x over previous
//
#include <hip/hip_runtime.h>

#define NSMP 44100
#define NKNOT 100
#define NIV  (NKNOT - 1)      // 99 spline intervals
#define NCC 6
#define NAA 7
#define RING 1024             // logical ring; mirrored into 2048 floats
#define NTH 320
#define SEG ((NSMP + NTH - 1) / NTH)   // 138
// d_ws: recA (16B/smp) + recB (16B/smp) + recX (4B/smp)
#define WS_NEEDED ((size_t)NSMP * 36)

__device__ __forceinline__ float sigm(float x) { return 1.0f / (1.0f + expf(-x)); }

__device__ __forceinline__ void lean_barrier() {
    // drain LDS ops only (ring visibility); global loads/stores stay in flight
    asm volatile("s_waitcnt lgkmcnt(0)" ::: "memory");
    __builtin_amdgcn_s_barrier();
    __builtin_amdgcn_sched_barrier(0);
}

// =====================  shared prep (A, B, B')  ============================
__device__ __forceinline__ void prep_spline(
    const float* __restrict__ dlf, const float* __restrict__ rg,
    const float* __restrict__ rcf,
    float (*P)[NAA], float (*M)[NAA], float* CPs, float* IMs,
    float4 (*CO)[8], int* s_minz, int tid)
{
    const float H = 1.0f / 99.0f;
    if (tid < NKNOT) {
        float g = sigm(rg[0]);
        float s[NCC];
        float sum = 0.0f;
#pragma unroll
        for (int j = 0; j < NCC; ++j) { s[j] = sigm(rcf[tid * NCC + j]); sum += s[j]; }
        P[tid][0] = dlf[tid];
#pragma unroll
        for (int j = 0; j < NCC; ++j) P[tid][j + 1] = s[j] / sum * g;
    }
    // Thomas c' coefficients converge by ~10 iterations -> parallel
    if (tid < NKNOT - 2) {
        float cp = 0.25f;
        int n = tid; if (n > 10) n = 10;
        for (int k = 0; k < n; ++k) cp = 1.0f / (4.0f - cp);
        CPs[tid] = cp;
    }
    __syncthreads();
    if (tid >= 1 && tid < NKNOT - 2) IMs[tid] = 99.0f / (4.0f - CPs[tid - 1]);
    __syncthreads();
    if (tid < NAA) {
        int c = tid;
        float rhs0  = 6.0f * (P[2][c] - 2.0f * P[1][c] + P[0][c]) * 99.0f;
        float dprev = rhs0 * 24.75f;
        M[1][c] = dprev;
        for (int i = 1; i < NKNOT - 2; ++i) {
            float rhs = 6.0f * (P[i + 2][c] - 2.0f * P[i + 1][c] + P[i][c]) * 99.0f;
            float d   = (rhs - H * dprev) * IMs[i];
            M[i + 1][c] = d;
            dprev = d;
        }
        float nxt = M[NKNOT - 2][c];
        for (int i = NKNOT - 4; i >= 0; --i) {
            float v = M[i + 1][c] - CPs[i] * nxt;
            M[i + 1][c] = v;
            nxt = v;
        }
        M[0][c] = 0.0f;
        M[NKNOT - 1][c] = 0.0f;
    }
    __syncthreads();
    // min-delay lower bound: s(x) >= min(y0,y1) - (h^2/8) max|s''|
    if (tid < NIV) {
        float lb = fminf(P[tid][0], P[tid + 1][0])
                 - (H * H * 0.125f) * fmaxf(fabsf(M[tid][0]), fabsf(M[tid + 1][0]));
        atomicMin(s_minz, (int)floorf(lb));
    }
    for (int iv = tid; iv < NIV; iv += blockDim.x) {
#pragma unroll
        for (int c = 0; c < NAA; ++c) {
            float y0 = P[iv][c], y1 = P[iv + 1][c];
            float m0 = M[iv][c], m1 = M[iv + 1][c];
            float b  = (y1 - y0) * 99.0f - H * (2.0f * m0 + m1) * (1.0f / 6.0f);
            CO[iv][c] = make_float4(y0, b, 0.5f * m0, (m1 - m0) * (99.0f / 6.0f));
        }
    }
    __syncthreads();
}

// ============================  fast kernel  ================================

__global__ __launch_bounds__(NTH, 1) void diffks_fast(
    const float* __restrict__ dlf, const float* __restrict__ rg,
    const float* __restrict__ rcf, const float* __restrict__ exc,
    const float* __restrict__ ecoef, float* __restrict__ out,
    float4* __restrict__ recA, float4* __restrict__ recB,
    float* __restrict__ recX)
{
    __shared__ float  P[NKNOT][NAA];
    __shared__ float  M[NKNOT][NAA];
    __shared__ float4 CO[NIV][8];
    __shared__ float  ring[2 * RING];
    __shared__ float  CPs[NKNOT - 2];
    __shared__ float  IMs[NKNOT - 2];
    __shared__ float  wpS[NTH / 64], wqS[NTH / 64];
    __shared__ int    s_minz;

    const int tid  = threadIdx.x;
    const int lane = tid & 63;
    const int wav  = tid >> 6;
    const float H   = 1.0f / 99.0f;
    const float INV = 1.0f / (float)(NSMP - 1);

    if (tid == 0) s_minz = 0x7fffffff;
    for (int i = tid; i < 2 * RING; i += NTH) ring[i] = 0.0f;

    prep_spline(dlf, rg, rcf, P, M, CPs, IMs, CO, &s_minz, tid);

    // ---- Phase C: tap records for ALL samples -> recA/recB (d_ws) --------
    // (R8-proven: per-thread, cidx-cached CO registers.)
    {
        int start = tid * SEG;
        int end   = min(start + SEG, NSMP);
        int cidx = -1;
        float4 k0, k1, k2, k3, k4, k5, k6;
        k0 = k1 = k2 = k3 = k4 = k5 = k6 = make_float4(0.f, 0.f, 0.f, 0.f);
        for (int t = start; t < end; ++t) {
            float tt = (float)t * INV;
            int idx = (int)(tt * 99.0f); if (idx > NIV - 1) idx = NIV - 1;
            if (idx != cidx) {
                k0 = CO[idx][0]; k1 = CO[idx][1]; k2 = CO[idx][2]; k3 = CO[idx][3];
                k4 = CO[idx][4]; k5 = CO[idx][5]; k6 = CO[idx][6];
                cidx = idx;
            }
            float f = tt - (float)idx * H;
            float r0 = k0.x + f * (k0.y + f * (k0.z + f * k0.w));
            float r1 = k1.x + f * (k1.y + f * (k1.z + f * k1.w));
            float r2 = k2.x + f * (k2.y + f * (k2.z + f * k2.w));
            float r3 = k3.x + f * (k3.y + f * (k3.z + f * k3.w));
            float r4 = k4.x + f * (k4.y + f * (k4.z + f * k4.w));
            float r5 = k5.x + f * (k5.y + f * (k5.z + f * k5.w));
            float r6 = k6.x + f * (k6.y + f * (k6.z + f * k6.w));
            float fl = floorf(r0);
            float alfa = r0 - fl, om = 1.0f - alfa;
            // reversed taps: w_d multiplies ring[ra + d]
            float w6 = -om * r1;
            float w5 = -(alfa * r1 + om * r2);
            float w4 = -(alfa * r2 + om * r3);
            float w3 = -(alfa * r3 + om * r4);
            float w2 = -(alfa * r4 + om * r5);
            float w1 = -(alfa * r5 + om * r6);
            float w0 = -alfa * r6;
            int ra = (t - 1 - (int)fl - 6) & (RING - 1);
            recA[t] = make_float4(w0, w1, w2, w3);
            recB[t] = make_float4(w4, w5, w6, __int_as_float(ra));
        }
    }

    // ---- Phase D: order-1 LPC (segmented affine scan); x2 -> recX --------
    {
        int start = tid * SEG;
        int end   = min(start + SEG, NSMP);
        float p = 1.0f, q = 0.0f;
#pragma unroll 4
        for (int t = start; t < end; ++t) {
            float a2 = ecoef[t];
            q = fmaf(-a2, q, exc[t]);
            p *= -a2;
        }
#pragma unroll
        for (int d = 1; d < 64; d <<= 1) {
            float pp = __shfl_up(p, d);
            float qq = __shfl_up(q, d);
            if (lane >= d) { q = fmaf(p, qq, q); p *= pp; }
        }
        if (lane == 63) { wpS[wav] = p; wqS[wav] = q; }
        float pe = __shfl_up(p, 1);
        float qe = __shfl_up(q, 1);
        if (lane == 0) { pe = 1.0f; qe = 0.0f; }
        __syncthreads();
        float v = 0.0f;
        for (int w = 0; w < wav; ++w) v = fmaf(wpS[w], v, wqS[w]);
        float y = fmaf(pe, v, qe);
#pragma unroll 4
        for (int t = start; t < end; ++t) {
            y = fmaf(-ecoef[t], y, exc[t]);
            recX[t] = y;                       // x2 staged in d_ws, NOT out
        }
    }
    __syncthreads();   // recs + x2 + s_minz all visible (full drain, once)

    // ---- Phase E: SINGLE WAVE, zero barriers, zero out-aliasing ----------
    // Loads touch only recA/recB/recX (read-only in E, distinct restrict
    // pointers from out) -> the out[] stores are fire-and-forget and the
    // next-window prefetch needs no vmcnt ordering against them. Chain per
    // window = ring ds_reads + FMA + ds_writes + one lgkm drain.
    if (tid >= 64) return;                     // waves 1..4 done

    int C = s_minz + 1;
    if (C > 320) C = 320;
    if (C < 1)  C = 1;
    const int NW = (NSMP + C - 1) / C;

    float4 a[5], b[5];
    float  x[5];
#pragma unroll
    for (int r = 0; r < 5; ++r) {
        int pos = r * 64 + lane;
        int tc = (pos < C) ? pos : 0;
        a[r] = recA[tc]; b[r] = recB[tc]; x[r] = recX[tc];
    }

#pragma unroll 1
    for (int w = 0; w < NW; ++w) {
        // prefetch window w+1 (pure reads of rec*, no ordering vs out stores)
        float4 na[5], nb[5];
        float  nx[5];
#pragma unroll
        for (int r = 0; r < 5; ++r) {
            int pos = r * 64 + lane;
            int t = (w + 1) * C + pos;
            int tc = (pos < C && t < NSMP) ? t : 0;
            na[r] = recA[tc]; nb[r] = recB[tc]; nx[r] = recX[tc];
        }
        // current window: ring reads + FMA tree + ring/mirror/out writes
#pragma unroll
        for (int r = 0; r < 5; ++r) {
            int pos = r * 64 + lane;
            int t = w * C + pos;
            const float* rp = &ring[(unsigned)__float_as_int(b[r].w)];
            float y0 = rp[0], y1 = rp[1], y2 = rp[2], y3 = rp[3];
            float y4 = rp[4], y5 = rp[5], y6 = rp[6];
            float s = ((a[r].x * y0 + a[r].y * y1) + (a[r].z * y2 + a[r].w * y3))
                    + ((b[r].x * y4 + b[r].y * y5) + b[r].z * y6);
            float acc = x[r] - s;
            if (pos < C && t < NSMP) {
                int wi = t & (RING - 1);
                ring[wi]        = acc;
                ring[wi + RING] = acc;   // mirror: reads never wrap
                out[t] = acc;            // fire-and-forget global store
            }
        }
        // write -> next-window-read ordering within the wave (LDS only)
        asm volatile("s_waitcnt lgkmcnt(0)" ::: "memory");
        __builtin_amdgcn_sched_barrier(0);
#pragma unroll
        for (int r = 0; r < 5; ++r) { a[r] = na[r]; b[r] = nb[r]; x[r] = nx[r]; }
    }
}

// ================  fallback (round-4 proven path, no d_ws)  ================

#define FNTH 320
#define FSEG ((NSMP + FNTH - 1) / FNTH)
#define FGW 8

__device__ __forceinline__ void compute_rec_f(const float4 (*CO)[8], int t, bool a,
                                              float* wr, int* raOut) {
    const float H   = 1.0f / 99.0f;
    const float INV = 1.0f / (float)(NSMP - 1);
    if (!a) {
#pragma unroll
        for (int d = 0; d < NAA; ++d) wr[d] = 0.0f;
        *raOut = 0;
        return;
    }
    float tt = (float)t * INV;
    int idx = (int)(tt * 99.0f); if (idx > NIV - 1) idx = NIV - 1;
    float f = tt - (float)idx * H;
    float r[NAA];
#pragma unroll
    for (int c = 0; c < NAA; ++c) {
        float4 k = CO[idx][c];
        r[c] = k.x + f * (k.y + f * (k.z + f * k.w));
    }
    float fl = floorf(r[0]);
    float alfa = r[0] - fl, om = 1.0f - alfa;
    wr[6] = -om * r[1];
    wr[5] = -(alfa * r[1] + om * r[2]);
    wr[4] = -(alfa * r[2] + om * r[3]);
    wr[3] = -(alfa * r[3] + om * r[4]);
    wr[2] = -(alfa * r[4] + om * r[5]);
    wr[1] = -(alfa * r[5] + om * r[6]);
    wr[0] = -alfa * r[6];
    *raOut = (t - 1 - (int)fl - 6) & (RING - 1);
}

__global__ __launch_bounds__(FNTH, 1) void diffks_fallback(
    const float* __restrict__ dlf, const float* __restrict__ rg,
    const float* __restrict__ rcf, const float* __restrict__ exc,
    const float* __restrict__ ecoef, float* __restrict__ out)
{
    __shared__ float  P[NKNOT][NAA];
    __shared__ float  M[NKNOT][NAA];
    __shared__ float4 CO[NIV][8];
    __shared__ float  ring[2 * RING];
    __shared__ float  CPs[NKNOT - 2];
    __shared__ float  IMs[NKNOT - 2];
    __shared__ float  wpS[FNTH / 64], wqS[FNTH / 64];
    __shared__ int    s_minz;

    const int tid  = threadIdx.x;
    const int lane = tid & 63;
    const int wav  = tid >> 6;

    if (tid == 0) s_minz = 0x7fffffff;
    for (int i = tid; i < 2 * RING; i += FNTH) ring[i] = 0.0f;

    prep_spline(dlf, rg, rcf, P, M, CPs, IMs, CO, &s_minz, tid);

    {
        int start = tid * FSEG;
        int end   = min(start + FSEG, NSMP);
        float p = 1.0f, q = 0.0f;
#pragma unroll 4
        for (int t = start; t < end; ++t) {
            float a2 = ecoef[t];
            q = fmaf(-a2, q, exc[t]);
            p *= -a2;
        }
#pragma unroll
        for (int d = 1; d < 64; d <<= 1) {
            float pp = __shfl_up(p, d);
            float qq = __shfl_up(q, d);
            if (lane >= d) { q = fmaf(p, qq, q); p *= pp; }
        }
        if (lane == 63) { wpS[wav] = p; wqS[wav] = q; }
        float pe = __shfl_up(p, 1);
        float qe = __shfl_up(q, 1);
        if (lane == 0) { pe = 1.0f; qe = 0.0f; }
        __syncthreads();
        float v = 0.0f;
        for (int w = 0; w < wav; ++w) v = fmaf(wpS[w], v, wqS[w]);
        float y = fmaf(pe, v, qe);
#pragma unroll 4
        for (int t = start; t < end; ++t) {
            y = fmaf(-ecoef[t], y, exc[t]);
            out[t] = y;
        }
    }
    __syncthreads();

    int C = s_minz + 1;
    if (C > FNTH) C = FNTH;
    if (C < 1)  C = 1;
    const int NW   = (NSMP + C - 1) / C;
    const int NCH  = (NW + FGW - 1) / FGW;
    const int step = FGW * C;

    float  wA[FGW][NAA];
    int    raA[FGW];
    float  xsA[FGW];
    int    wiA[FGW];
    bool   aA[FGW];
    float* opA[FGW];
#pragma unroll
    for (int g = 0; g < FGW; ++g) {
        int t = g * C + tid;
        bool a = (tid < C) && (t < NSMP);
        compute_rec_f(CO, t, a, wA[g], &raA[g]);
        xsA[g]  = a ? out[t] : 0.0f;
        wiA[g]  = t & (RING - 1);
        aA[g]   = a;
        opA[g]  = out + t;
    }
    for (int ch = 0; ch < NCH; ++ch) {
        const int Wn = (ch + 1) * step;
        float  nx[FGW]; int ntv[FGW]; int nwi[FGW]; bool nav[FGW]; float* nop[FGW];
#pragma unroll
        for (int g = 0; g < FGW; ++g) {
            int tn = Wn + g * C + tid;
            bool an = (tid < C) && (tn < NSMP);
            nx[g]  = an ? out[tn] : 0.0f;
            ntv[g] = tn; nwi[g] = tn & (RING - 1); nav[g] = an; nop[g] = out + tn;
        }
        float wB[FGW][NAA]; int raB[FGW];
#pragma unroll
        for (int g = 0; g < FGW; ++g) {
            const float* rp = &ring[(unsigned)raA[g]];
            float y0 = rp[0], y1 = rp[1], y2 = rp[2], y3 = rp[3];
            float y4 = rp[4], y5 = rp[5], y6 = rp[6];
            compute_rec_f(CO, ntv[g], nav[g], wB[g], &raB[g]);
            float s = ((wA[g][0] * y0 + wA[g][1] * y1) + (wA[g][2] * y2 + wA[g][3] * y3))
                    + ((wA[g][4] * y4 + wA[g][5] * y5) + wA[g][6] * y6);
            float acc = xsA[g] - s;
            if (aA[g]) {
                ring[wiA[g]] = acc;
                ring[wiA[g] + RING] = acc;
                *opA[g] = acc;
            }
            lean_barrier();
        }
#pragma unroll
        for (int g = 0; g < FGW; ++g) {
#pragma unroll
            for (int d = 0; d < NAA; ++d) wA[g][d] = wB[g][d];
            raA[g] = raB[g]; xsA[g] = nx[g]; wiA[g] = nwi[g];
            aA[g] = nav[g]; opA[g] = nop[g];
        }
    }
}

extern "C" void kernel_launch(void* const* d_in, const int* in_sizes, int n_in,
                              void* d_out, int out_size, void* d_ws, size_t ws_size,
                              hipStream_t stream) {
    const float* dlf   = (const float*)d_in[0];
    const float* rg    = (const float*)d_in[1];
    const float* rcf   = (const float*)d_in[2];
    const float* exc   = (const float*)d_in[3];
    const float* ecoef = (const float*)d_in[4];
    float* out = (float*)d_out;

    if (d_ws != nullptr && ws_size >= WS_NEEDED) {
        float4* recA = (float4*)d_ws;
        float4* recB = (float4*)((char*)d_ws + (size_t)NSMP * 16);
        float*  recX = (float*)((char*)d_ws + (size_t)NSMP * 32);
        hipLaunchKernelGGL(diffks_fast, dim3(1), dim3(NTH), 0, stream,
                           dlf, rg, rcf, exc, ecoef, out, recA, recB, recX);
    } else {
        hipLaunchKernelGGL(diffks_fallback, dim3(1), dim3(FNTH), 0, stream,
                           dlf, rg, rcf, exc, ecoef, out);
    }
}

// Round 16
// 136.257 us; speedup vs baseline: 1.7909x; 1.7536x over previous
//
#include <hip/hip_runtime.h>

#define NSMP 44100
#define NKNOT 100
#define NIV  (NKNOT - 1)      // 99 spline intervals
#define NCC 6                 // NC in reference
#define NAA 7                 // NA in reference = number of taps
#define RING 1024             // logical ring; mirrored into 2048 floats
#define NTH 320
#define SEG ((NSMP + NTH - 1) / NTH)   // 138
#define GW 8                  // windows per chunk

__device__ __forceinline__ float sigm(float x) { return 1.0f / (1.0f + expf(-x)); }

__device__ __forceinline__ void lean_barrier() {
    // drain LDS ops only (ring visibility); vmcnt (global loads/stores) stays in flight
    asm volatile("s_waitcnt lgkmcnt(0)" ::: "memory");
    __builtin_amdgcn_s_barrier();
    __builtin_amdgcn_sched_barrier(0);
}

// taps + ring base for sample t. wr[d] multiplies ring value y[base-6+d].
__device__ __forceinline__ void compute_rec(const float4 (*CO)[8], int t, bool a,
                                            float* wr, int* raOut) {
    const float H   = 1.0f / 99.0f;
    const float INV = 1.0f / (float)(NSMP - 1);
    if (!a) {
#pragma unroll
        for (int d = 0; d < NAA; ++d) wr[d] = 0.0f;
        *raOut = 0;
        return;
    }
    float tt = (float)t * INV;
    int idx = (int)(tt * 99.0f); if (idx > NIV - 1) idx = NIV - 1;
    float f = tt - (float)idx * H;
    float r[NAA];
#pragma unroll
    for (int c = 0; c < NAA; ++c) {
        float4 k = CO[idx][c];
        r[c] = k.x + f * (k.y + f * (k.z + f * k.w));
    }
    float fl = floorf(r[0]);
    float alfa = r[0] - fl, om = 1.0f - alfa;
    // v_j multiplies y[t-1-z-j]; stored reversed: wr[d] = v_{6-d}
    wr[6] = -om * r[1];
    wr[5] = -(alfa * r[1] + om * r[2]);
    wr[4] = -(alfa * r[2] + om * r[3]);
    wr[3] = -(alfa * r[3] + om * r[4]);
    wr[2] = -(alfa * r[4] + om * r[5]);
    wr[1] = -(alfa * r[5] + om * r[6]);
    wr[0] = -alfa * r[6];
    *raOut = (t - 1 - (int)fl - 6) & (RING - 1);
}

__global__ __launch_bounds__(NTH, 1) void diffks_kernel(
    const float* __restrict__ dlf, const float* __restrict__ rg,
    const float* __restrict__ rcf, const float* __restrict__ exc,
    const float* __restrict__ ecoef, float* __restrict__ out)
{
    __shared__ float  P[NKNOT][NAA];
    __shared__ float  M[NKNOT][NAA];
    __shared__ float4 CO[NIV][8];
    __shared__ float  ring[2 * RING];            // mirrored
    __shared__ float  CPs[NKNOT - 2];
    __shared__ float  IMs[NKNOT - 2];
    __shared__ float  wpS[NTH / 64], wqS[NTH / 64];
    __shared__ int    s_minz;

    const int tid  = threadIdx.x;
    const int lane = tid & 63;
    const int wav  = tid >> 6;
    const float H  = 1.0f / 99.0f;

    if (tid == 0) s_minz = 0x7fffffff;
    for (int i = tid; i < 2 * RING; i += NTH) ring[i] = 0.0f;

    // ---------------- Phase A: knot params --------------------------------
    if (tid < NKNOT) {
        float g = sigm(rg[0]);
        float s[NCC];
        float sum = 0.0f;
#pragma unroll
        for (int j = 0; j < NCC; ++j) { s[j] = sigm(rcf[tid * NCC + j]); sum += s[j]; }
        P[tid][0] = dlf[tid];
#pragma unroll
        for (int j = 0; j < NCC; ++j) P[tid][j + 1] = s[j] / sum * g;
    }
    // Thomas c' coefficients: converge by ~10 iters -> compute in parallel
    if (tid < NKNOT - 2) {
        float cp = 0.25f;
        int n = tid; if (n > 10) n = 10;
        for (int k = 0; k < n; ++k) cp = 1.0f / (4.0f - cp);
        CPs[tid] = cp;
    }
    __syncthreads();
    if (tid >= 1 && tid < NKNOT - 2) IMs[tid] = 99.0f / (4.0f - CPs[tid - 1]);
    __syncthreads();

    // ---------------- Phase B: M solve (7 cols) ---------------------------
    if (tid < NAA) {
        int c = tid;
        float rhs0  = 6.0f * (P[2][c] - 2.0f * P[1][c] + P[0][c]) * 99.0f;
        float dprev = rhs0 * 24.75f;
        M[1][c] = dprev;
        for (int i = 1; i < NKNOT - 2; ++i) {
            float rhs = 6.0f * (P[i + 2][c] - 2.0f * P[i + 1][c] + P[i][c]) * 99.0f;
            float d   = (rhs - H * dprev) * IMs[i];
            M[i + 1][c] = d;
            dprev = d;
        }
        float nxt = M[NKNOT - 2][c];
        for (int i = NKNOT - 4; i >= 0; --i) {
            float v = M[i + 1][c] - CPs[i] * nxt;
            M[i + 1][c] = v;
            nxt = v;
        }
        M[0][c] = 0.0f;
        M[NKNOT - 1][c] = 0.0f;
    }
    __syncthreads();

    // ---- safe min-delay bound from knots ---------------------------------
    if (tid < NIV) {
        float lb = fminf(P[tid][0], P[tid + 1][0])
                 - (H * H * 0.125f) * fmaxf(fabsf(M[tid][0]), fabsf(M[tid + 1][0]));
        atomicMin(&s_minz, (int)floorf(lb));
    }

    // ---------------- Phase B': per-interval poly coefficients ------------
    for (int iv = tid; iv < NIV; iv += NTH) {
#pragma unroll
        for (int c = 0; c < NAA; ++c) {
            float y0 = P[iv][c], y1 = P[iv + 1][c];
            float m0 = M[iv][c], m1 = M[iv + 1][c];
            float b  = (y1 - y0) * 99.0f - H * (2.0f * m0 + m1) * (1.0f / 6.0f);
            CO[iv][c] = make_float4(y0, b, 0.5f * m0, (m1 - m0) * (99.0f / 6.0f));
        }
    }
    __syncthreads();

    // ---------------- Phase D: order-1 LPC (segmented affine scan) --------
    {
        int start = tid * SEG;
        int end   = min(start + SEG, NSMP);
        float p = 1.0f, q = 0.0f;
#pragma unroll 4
        for (int t = start; t < end; ++t) {
            float a2 = ecoef[t];
            q = fmaf(-a2, q, exc[t]);
            p *= -a2;
        }
#pragma unroll
        for (int d = 1; d < 64; d <<= 1) {
            float pp = __shfl_up(p, d);
            float qq = __shfl_up(q, d);
            if (lane >= d) { q = fmaf(p, qq, q); p *= pp; }
        }
        if (lane == 63) { wpS[wav] = p; wqS[wav] = q; }
        float pe = __shfl_up(p, 1);
        float qe = __shfl_up(q, 1);
        if (lane == 0) { pe = 1.0f; qe = 0.0f; }
        __syncthreads();
        float v = 0.0f;
        for (int w = 0; w < wav; ++w) v = fmaf(wpS[w], v, wqS[w]);
        float y = fmaf(pe, v, qe);
#pragma unroll 4
        for (int t = start; t < end; ++t) {
            y = fmaf(-ecoef[t], y, exc[t]);
            out[t] = y;                        // stage x2 in d_out
        }
    }
    __syncthreads();   // x2 + s_minz visible

    // ---------------- Phase E: serial windows (proven-best structure) -----
    int C = s_minz + 1;
    if (C > NTH) C = NTH;
    if (C < 1)  C = 1;
    const int NW   = (NSMP + C - 1) / C;
    const int NCH  = (NW + GW - 1) / GW;
    const int step = GW * C;

    float  wA[GW][NAA];
    int    raA[GW];
    float  xsA[GW];
    int    wiA[GW];
    bool   aA[GW];
    float* opA[GW];
#pragma unroll
    for (int g = 0; g < GW; ++g) {
        int t = g * C + tid;
        bool a = (tid < C) && (t < NSMP);
        compute_rec(CO, t, a, wA[g], &raA[g]);
        xsA[g]  = a ? out[t] : 0.0f;
        wiA[g]  = t & (RING - 1);
        aA[g]   = a;
        opA[g]  = out + t;
    }

    for (int ch = 0; ch < NCH; ++ch) {
        const int Wn = (ch + 1) * step;
        // next-chunk prefetch: x2 loads + per-window constants (off-chain)
        float  nx[GW];
        int    ntv[GW];
        int    nwi[GW];
        bool   nav[GW];
        float* nop[GW];
#pragma unroll
        for (int g = 0; g < GW; ++g) {
            int tn = Wn + g * C + tid;
            bool an = (tid < C) && (tn < NSMP);
            nx[g]  = an ? out[tn] : 0.0f;
            ntv[g] = tn;
            nwi[g] = tn & (RING - 1);
            nav[g] = an;
            nop[g] = out + tn;
        }
        float wB[GW][NAA];
        int   raB[GW];
        // serial windows; next-chunk tap precompute fused into the ds_read shadow
#pragma unroll
        for (int g = 0; g < GW; ++g) {
            const float* rp = &ring[(unsigned)raA[g]];
            float y0 = rp[0], y1 = rp[1], y2 = rp[2], y3 = rp[3];
            float y4 = rp[4], y5 = rp[5], y6 = rp[6];
            {   // independent VALU: fills the LDS latency shadow
                compute_rec(CO, ntv[g], nav[g], wB[g], &raB[g]);
            }
            float s = ((wA[g][0] * y0 + wA[g][1] * y1) + (wA[g][2] * y2 + wA[g][3] * y3))
                    + ((wA[g][4] * y4 + wA[g][5] * y5) + wA[g][6] * y6);
            float acc = xsA[g] - s;
            if (aA[g]) {
                ring[wiA[g]] = acc;
                ring[wiA[g] + RING] = acc;   // mirror: reads never wrap
                *opA[g] = acc;               // store off-chain (vmcnt not drained)
            }
            lean_barrier();
        }
#pragma unroll
        for (int g = 0; g < GW; ++g) {
#pragma unroll
            for (int d = 0; d < NAA; ++d) wA[g][d] = wB[g][d];
            raA[g] = raB[g];
            xsA[g] = nx[g];
            wiA[g] = nwi[g];
            aA[g]  = nav[g];
            opA[g] = nop[g];
        }
    }
}

extern "C" void kernel_launch(void* const* d_in, const int* in_sizes, int n_in,
                              void* d_out, int out_size, void* d_ws, size_t ws_size,
                              hipStream_t stream) {
    const float* dlf   = (const float*)d_in[0];
    const float* rg    = (const float*)d_in[1];
    const float* rcf   = (const float*)d_in[2];
    const float* exc   = (const float*)d_in[3];
    const float* ecoef = (const float*)d_in[4];
    float* out = (float*)d_out;
    hipLaunchKernelGGL(diffks_kernel, dim3(1), dim3(NTH), 0, stream,
                       dlf, rg, rcf, exc, ecoef, out);
}